// Round 1
// baseline (463.953 us; speedup 1.0000x reference)
//
#include <hip/hip_runtime.h>

#define HID  24
#define TT   262
#define KOUT 256
#define BPB  8      // batch elements per block (one 32-lane group each)
#define PSTR 260    // padded p stride (breaks 8-way bank conflict on lane0 writes)

typedef float v2f __attribute__((ext_vector_type(2)));

__device__ __forceinline__ float fast_sigmoid(float x){
    return __builtin_amdgcn_rcpf(1.0f + __expf(-x));
}
__device__ __forceinline__ float fast_tanh(float x){
    float e = __expf(2.0f * x);
    return 1.0f - 2.0f * __builtin_amdgcn_rcpf(e + 1.0f);
}

// One GRU direction for one batch element per 32-lane group.
// lane i (<24) owns hidden unit i; lanes 24..31 run with zeroed weights (stay 0).
// All cross-lane exchange of h goes through hrow (LDS) wave-synchronously: the
// 24 producer lanes and all consumer lanes are in the same wave, so program
// order + lgkmcnt waits give correctness with no barriers in the scan loop.
template<bool FWD>
__device__ __forceinline__ void run_dir(
    const float* xrow,            // LDS: this batch element's x, (TT,2)
    float* hrow,                  // LDS: 32 floats, h state
    float* prow,                  // LDS: PSTR floats, per-t projection partials
    const float* __restrict__ w_ih, const float* __restrict__ w_hh,
    const float* __restrict__ b_ih, const float* __restrict__ b_hh,
    const float* __restrict__ w_out, int lane)
{
    const int   ii  = (lane < HID) ? lane : 0;
    const float msk = (lane < HID) ? 1.0f : 0.0f;

    // 3 rows (r,z,n) of w_hh in registers as float2 pairs (v_pk_fma candidate)
    v2f wr2[12], wz2[12], wn2[12];
    {
        const float4* r4 = reinterpret_cast<const float4*>(w_hh + ii * HID);
        const float4* z4 = reinterpret_cast<const float4*>(w_hh + (HID + ii) * HID);
        const float4* n4 = reinterpret_cast<const float4*>(w_hh + (2 * HID + ii) * HID);
        #pragma unroll
        for (int j = 0; j < 6; ++j){
            float4 a = r4[j], b = z4[j], c = n4[j];
            wr2[2*j]   = v2f{a.x * msk, a.y * msk};
            wr2[2*j+1] = v2f{a.z * msk, a.w * msk};
            wz2[2*j]   = v2f{b.x * msk, b.y * msk};
            wz2[2*j+1] = v2f{b.z * msk, b.w * msk};
            wn2[2*j]   = v2f{c.x * msk, c.y * msk};
            wn2[2*j+1] = v2f{c.z * msk, c.w * msk};
        }
    }
    // biases: r/z fold b_ih+b_hh; n keeps them separate (b_hh_n sits inside r*(...))
    const float br   = (b_ih[ii]           + b_hh[ii])           * msk;
    const float bz   = (b_ih[HID + ii]     + b_hh[HID + ii])     * msk;
    const float bin  =  b_ih[2 * HID + ii] * msk;
    const float bhn  =  b_hh[2 * HID + ii] * msk;
    const float wir0 = w_ih[2 * ii] * msk,             wir1 = w_ih[2 * ii + 1] * msk;
    const float wiz0 = w_ih[2 * (HID + ii)] * msk,     wiz1 = w_ih[2 * (HID + ii) + 1] * msk;
    const float win0 = w_ih[2 * (2 * HID + ii)] * msk, win1 = w_ih[2 * (2 * HID + ii) + 1] * msk;
    const float pw   = w_out[(FWD ? 0 : HID) + ii] * msk;

    float hself = 0.0f;
    hrow[lane] = 0.0f;

    int t = FWD ? 0 : (TT - 1);
    const int steps = FWD ? KOUT : TT;   // fwd: t>=256 never affects the sliced output
    for (int s = 0; s < steps; ++s){
        const float2 xv = *reinterpret_cast<const float2*>(xrow + 2 * t);

        v2f gr2 = {0.f, 0.f}, gz2 = {0.f, 0.f}, gn2 = {0.f, 0.f};
        const float4* h4 = reinterpret_cast<const float4*>(hrow);
        #pragma unroll
        for (int j = 0; j < 6; ++j){
            float4 a = h4[j];
            v2f h0 = {a.x, a.y}, h1 = {a.z, a.w};
            gr2 = h0 * wr2[2*j] + gr2;  gr2 = h1 * wr2[2*j+1] + gr2;
            gz2 = h0 * wz2[2*j] + gz2;  gz2 = h1 * wz2[2*j+1] + gz2;
            gn2 = h0 * wn2[2*j] + gn2;  gn2 = h1 * wn2[2*j+1] + gn2;
        }
        float gr  = br  + gr2.x + gr2.y + xv.x * wir0 + xv.y * wir1;
        float gz  = bz  + gz2.x + gz2.y + xv.x * wiz0 + xv.y * wiz1;
        float ghn = bhn + gn2.x + gn2.y;
        float gin = bin + xv.x * win0 + xv.y * win1;

        float r = fast_sigmoid(gr);
        float z = fast_sigmoid(gz);
        float n = fast_tanh(fmaf(r, ghn, gin));
        float hnew = n + z * (hself - n);   // (1-z)*n + z*h
        hself = hnew;
        hrow[lane] = hnew;

        // fold output projection: p(t) = sum_i h_i * w_out_part[i]
        float pv = hnew * pw;
        pv += __shfl_xor(pv, 1);
        pv += __shfl_xor(pv, 2);
        pv += __shfl_xor(pv, 4);
        pv += __shfl_xor(pv, 8);
        pv += __shfl_xor(pv, 16);
        if (FWD){
            if (lane == 0) prow[t] = pv;
        } else {
            if (lane == 0 && t < KOUT) prow[t] += pv;
        }
        __threadfence_block();   // order hrow write vs next step's reads (wave-local)
        t += FWD ? 1 : -1;
    }
}

__global__ __launch_bounds__(256, 4) void birnn_kernel(
    const float* __restrict__ x,
    const float* __restrict__ w_ih_f, const float* __restrict__ w_hh_f,
    const float* __restrict__ b_ih_f, const float* __restrict__ b_hh_f,
    const float* __restrict__ w_ih_b, const float* __restrict__ w_hh_b,
    const float* __restrict__ b_ih_b, const float* __restrict__ b_hh_b,
    const float* __restrict__ w_out,  const float* __restrict__ b_out,
    float* __restrict__ out)
{
    __shared__ float4 xs4[BPB * TT * 2 / 4];   // 16768 B staged x
    __shared__ float  hsm[BPB][32];            //  1024 B h state
    __shared__ float  psm[BPB][PSTR];          //  8320 B projection partials

    const int tid  = threadIdx.x;
    const int g    = tid >> 5;
    const int lane = tid & 31;
    const int b0   = blockIdx.x * BPB;

    // stage this block's 8 batch rows of x (contiguous 4192 floats), coalesced
    const float4* xg = reinterpret_cast<const float4*>(x + (size_t)b0 * (TT * 2));
    for (int i = tid; i < BPB * TT * 2 / 4; i += 256) xs4[i] = xg[i];
    __syncthreads();

    const float* xrow = reinterpret_cast<const float*>(xs4) + g * (TT * 2);
    run_dir<true >(xrow, hsm[g], psm[g], w_ih_f, w_hh_f, b_ih_f, b_hh_f, w_out, lane);
    run_dir<false>(xrow, hsm[g], psm[g], w_ih_b, w_hh_b, b_ih_b, b_hh_b, w_out, lane);
    __syncthreads();

    const float bo = b_out[0];
    for (int i = tid; i < BPB * KOUT; i += 256){
        int bl = i >> 8, t = i & 255;
        out[(size_t)(b0 + bl) * KOUT + t] = psm[bl][t] + bo;
    }
}

extern "C" void kernel_launch(void* const* d_in, const int* in_sizes, int n_in,
                              void* d_out, int out_size, void* d_ws, size_t ws_size,
                              hipStream_t stream)
{
    const float* x      = (const float*)d_in[0];
    const float* w_ih_f = (const float*)d_in[1];
    const float* w_hh_f = (const float*)d_in[2];
    const float* b_ih_f = (const float*)d_in[3];
    const float* b_hh_f = (const float*)d_in[4];
    const float* w_ih_b = (const float*)d_in[5];
    const float* w_hh_b = (const float*)d_in[6];
    const float* b_ih_b = (const float*)d_in[7];
    const float* b_hh_b = (const float*)d_in[8];
    const float* w_out  = (const float*)d_in[9];
    const float* b_out  = (const float*)d_in[10];
    float* out = (float*)d_out;

    birnn_kernel<<<dim3(8192 / BPB), dim3(256), 0, stream>>>(
        x, w_ih_f, w_hh_f, b_ih_f, b_hh_f,
        w_ih_b, w_hh_b, b_ih_b, b_hh_b, w_out, b_out, out);
}

// Round 2
// 459.132 us; speedup vs baseline: 1.0105x; 1.0105x over previous
//
#include <hip/hip_runtime.h>

#define HID  24
#define TT   262
#define KOUT 256
#define BPB  8      // batch elements per block (one 32-lane group each)
#define PSTR 260    // padded p stride

typedef float v2f __attribute__((ext_vector_type(2)));

// acc = a*b + acc (packed fp32, guaranteed v_pk_fma_f32)
#define PKFMA(acc, a, b) asm("v_pk_fma_f32 %0, %1, %2, %0" : "+v"(acc) : "v"(a), "v"(b))
// d = a*b (packed)
#define PKMUL(d, a, b)   asm("v_pk_mul_f32 %0, %1, %2"     : "=v"(d)   : "v"(a), "v"(b))

__device__ __forceinline__ float sig2(float x){   // sigma from pre-scaled arg: 1/(1+2^x)
    return __builtin_amdgcn_rcpf(1.0f + __builtin_amdgcn_exp2f(x));
}

// One GRU direction for one batch element per 32-lane group.
// lane i (<24) owns hidden unit i; lanes 24..31 carry zero weights (h stays 0).
// Cross-lane h exchange via LDS is wave-synchronous (no barriers in scan loop).
template<bool FWD>
__device__ __forceinline__ void run_dir(
    const float* xrow,            // LDS: this batch element's x, (TT,2)
    float* hrow,                  // LDS: 32 floats, h state
    float* prow,                  // LDS: PSTR floats, per-t projection partials
    const float* __restrict__ w_ih, const float* __restrict__ w_hh,
    const float* __restrict__ b_ih, const float* __restrict__ b_hh,
    const float* __restrict__ w_out, int lane)
{
    const int   ii  = (lane < HID) ? lane : 0;
    const float msk = (lane < HID) ? 1.0f : 0.0f;

    // Pre-scales: r,z rows by -log2(e) -> sigma(a) = 1/(1+2^A).
    // n rows (both hh and ih parts) by 2*log2(e) -> tanh(y) = 1 - 2/(1+2^Y).
    const float SRZ = -1.4426950408889634f * msk;
    const float SN  =  2.8853900817779268f * msk;

    // --- weights in NAMED registers (no arrays -> no scratch) ---
    const float4* r4 = reinterpret_cast<const float4*>(w_hh + ii * HID);
    const float4* z4 = reinterpret_cast<const float4*>(w_hh + (HID + ii) * HID);
    const float4* n4 = reinterpret_cast<const float4*>(w_hh + (2 * HID + ii) * HID);
    v2f wr0,wr1,wr2,wr3,wr4,wr5,wr6,wr7,wr8,wr9,wr10,wr11;
    v2f wz0,wz1,wz2,wz3,wz4,wz5,wz6,wz7,wz8,wz9,wz10,wz11;
    v2f wn0,wn1,wn2,wn3,wn4,wn5,wn6,wn7,wn8,wn9,wn10,wn11;
#define LDW(d0, d1, Q, S) { float4 q_ = (Q); d0 = v2f{q_.x*(S), q_.y*(S)}; d1 = v2f{q_.z*(S), q_.w*(S)}; }
    LDW(wr0, wr1, r4[0], SRZ) LDW(wr2, wr3, r4[1], SRZ) LDW(wr4, wr5, r4[2], SRZ)
    LDW(wr6, wr7, r4[3], SRZ) LDW(wr8, wr9, r4[4], SRZ) LDW(wr10,wr11,r4[5], SRZ)
    LDW(wz0, wz1, z4[0], SRZ) LDW(wz2, wz3, z4[1], SRZ) LDW(wz4, wz5, z4[2], SRZ)
    LDW(wz6, wz7, z4[3], SRZ) LDW(wz8, wz9, z4[4], SRZ) LDW(wz10,wz11,z4[5], SRZ)
    LDW(wn0, wn1, n4[0], SN ) LDW(wn2, wn3, n4[1], SN ) LDW(wn4, wn5, n4[2], SN )
    LDW(wn6, wn7, n4[3], SN ) LDW(wn8, wn9, n4[4], SN ) LDW(wn10,wn11,n4[5], SN )
#undef LDW

    const v2f wxr = v2f{w_ih[2*ii] * SRZ,           w_ih[2*ii+1] * SRZ};
    const v2f wxz = v2f{w_ih[2*(HID+ii)] * SRZ,     w_ih[2*(HID+ii)+1] * SRZ};
    const v2f wxn = v2f{w_ih[2*(2*HID+ii)] * SN,    w_ih[2*(2*HID+ii)+1] * SN};
    const float br  = (b_ih[ii]       + b_hh[ii])       * SRZ;
    const float bz  = (b_ih[HID+ii]   + b_hh[HID+ii])   * SRZ;
    const float bnh =  b_hh[2*HID+ii] * SN;
    const float bni =  b_ih[2*HID+ii] * SN;
    const float pw  =  w_out[(FWD ? 0 : HID) + ii] * msk;

    float hself = 0.0f;
    hrow[lane] = 0.0f;
    asm volatile("" ::: "memory");

    const float4* h4 = reinterpret_cast<const float4*>(hrow);
    int t = FWD ? 0 : (TT - 1);
    const int steps = FWD ? KOUT : TT;   // fwd t>=256 never reaches the sliced output

    #pragma unroll 1
    for (int s = 0; s < steps; ++s){
        const v2f xv = *reinterpret_cast<const v2f*>(xrow + 2 * t);

        v2f ar, az, ai;
        PKMUL(ar, xv, wxr);
        PKMUL(az, xv, wxz);
        PKMUL(ai, xv, wxn);
        v2f an = v2f{bnh, 0.0f};

        float4 h; v2f h0, h1;
        h = h4[0]; h0 = v2f{h.x,h.y}; h1 = v2f{h.z,h.w};
        PKFMA(ar,h0,wr0); PKFMA(ar,h1,wr1); PKFMA(az,h0,wz0); PKFMA(az,h1,wz1); PKFMA(an,h0,wn0); PKFMA(an,h1,wn1);
        h = h4[1]; h0 = v2f{h.x,h.y}; h1 = v2f{h.z,h.w};
        PKFMA(ar,h0,wr2); PKFMA(ar,h1,wr3); PKFMA(az,h0,wz2); PKFMA(az,h1,wz3); PKFMA(an,h0,wn2); PKFMA(an,h1,wn3);
        h = h4[2]; h0 = v2f{h.x,h.y}; h1 = v2f{h.z,h.w};
        PKFMA(ar,h0,wr4); PKFMA(ar,h1,wr5); PKFMA(az,h0,wz4); PKFMA(az,h1,wz5); PKFMA(an,h0,wn4); PKFMA(an,h1,wn5);
        h = h4[3]; h0 = v2f{h.x,h.y}; h1 = v2f{h.z,h.w};
        PKFMA(ar,h0,wr6); PKFMA(ar,h1,wr7); PKFMA(az,h0,wz6); PKFMA(az,h1,wz7); PKFMA(an,h0,wn6); PKFMA(an,h1,wn7);
        h = h4[4]; h0 = v2f{h.x,h.y}; h1 = v2f{h.z,h.w};
        PKFMA(ar,h0,wr8); PKFMA(ar,h1,wr9); PKFMA(az,h0,wz8); PKFMA(az,h1,wz9); PKFMA(an,h0,wn8); PKFMA(an,h1,wn9);
        h = h4[5]; h0 = v2f{h.x,h.y}; h1 = v2f{h.z,h.w};
        PKFMA(ar,h0,wr10); PKFMA(ar,h1,wr11); PKFMA(az,h0,wz10); PKFMA(az,h1,wz11); PKFMA(an,h0,wn10); PKFMA(an,h1,wn11);

        float R  = ar.x + ar.y + br;
        float Z  = az.x + az.y + bz;
        float GN = an.x + an.y;          // bias folded into init
        float GI = ai.x + ai.y + bni;

        float r = sig2(R);
        float z = sig2(Z);
        float Y = fmaf(r, GN, GI);
        float n = fmaf(-2.0f, __builtin_amdgcn_rcpf(1.0f + __builtin_amdgcn_exp2f(Y)), 1.0f);
        float hnew = fmaf(z, hself - n, n);   // (1-z)*n + z*h
        hself = hnew;
        hrow[lane] = hnew;

        float pv = hnew * pw;
        pv += __shfl_xor(pv, 1);
        pv += __shfl_xor(pv, 2);
        pv += __shfl_xor(pv, 4);
        pv += __shfl_xor(pv, 8);
        pv += __shfl_xor(pv, 16);
        if (FWD){
            if (lane == 0) prow[t] = pv;
        } else {
            if (lane == 0 && t < KOUT) prow[t] += pv;
        }
        asm volatile("" ::: "memory");   // order hrow write vs next step's reads
        t += FWD ? 1 : -1;
    }
}

__global__ __launch_bounds__(256, 4) void birnn_kernel(
    const float* __restrict__ x,
    const float* __restrict__ w_ih_f, const float* __restrict__ w_hh_f,
    const float* __restrict__ b_ih_f, const float* __restrict__ b_hh_f,
    const float* __restrict__ w_ih_b, const float* __restrict__ w_hh_b,
    const float* __restrict__ b_ih_b, const float* __restrict__ b_hh_b,
    const float* __restrict__ w_out,  const float* __restrict__ b_out,
    float* __restrict__ out)
{
    __shared__ __align__(16) float4 xs4[BPB * TT * 2 / 4];   // 16768 B staged x
    __shared__ __align__(16) float  hsm[BPB][32];            //  1024 B h state
    __shared__ float  psm[BPB][PSTR];                        //  8320 B projection partials

    const int tid  = threadIdx.x;
    const int g    = tid >> 5;
    const int lane = tid & 31;
    const int b0   = blockIdx.x * BPB;

    // stage this block's 8 batch rows of x (contiguous 4192 floats), coalesced
    const float4* xg = reinterpret_cast<const float4*>(x + (size_t)b0 * (TT * 2));
    for (int i = tid; i < BPB * TT * 2 / 4; i += 256) xs4[i] = xg[i];
    __syncthreads();

    const float* xrow = reinterpret_cast<const float*>(xs4) + g * (TT * 2);
    run_dir<true >(xrow, hsm[g], psm[g], w_ih_f, w_hh_f, b_ih_f, b_hh_f, w_out, lane);
    run_dir<false>(xrow, hsm[g], psm[g], w_ih_b, w_hh_b, b_ih_b, b_hh_b, w_out, lane);
    __syncthreads();

    const float bo = b_out[0];
    for (int i = tid; i < BPB * KOUT; i += 256){
        int bl = i >> 8, t = i & 255;
        out[(size_t)(b0 + bl) * KOUT + t] = psm[bl][t] + bo;
    }
}

extern "C" void kernel_launch(void* const* d_in, const int* in_sizes, int n_in,
                              void* d_out, int out_size, void* d_ws, size_t ws_size,
                              hipStream_t stream)
{
    const float* x      = (const float*)d_in[0];
    const float* w_ih_f = (const float*)d_in[1];
    const float* w_hh_f = (const float*)d_in[2];
    const float* b_ih_f = (const float*)d_in[3];
    const float* b_hh_f = (const float*)d_in[4];
    const float* w_ih_b = (const float*)d_in[5];
    const float* w_hh_b = (const float*)d_in[6];
    const float* b_ih_b = (const float*)d_in[7];
    const float* b_hh_b = (const float*)d_in[8];
    const float* w_out  = (const float*)d_in[9];
    const float* b_out  = (const float*)d_in[10];
    float* out = (float*)d_out;

    birnn_kernel<<<dim3(8192 / BPB), dim3(256), 0, stream>>>(
        x, w_ih_f, w_hh_f, b_ih_f, b_hh_f,
        w_ih_b, w_hh_b, b_ih_b, b_hh_b, w_out, b_out, out);
}